// Round 3
// baseline (491.705 us; speedup 1.0000x reference)
//
#include <hip/hip_runtime.h>
#include <hip/hip_bf16.h>

// ---------------------------------------------------------------------------
// GANClassifier forward, fp32 baseline (round 2 resubmit: adaptive adjacency).
// Pipeline:
//   1. BN1 stats -> fold into GEMM1: Y = gelu(bn(nf) @ W1^T + c1)        [4096,1024]
//   2. BN2 stats -> GEMM2: X0 = gelu(bn(Y) @ W2^T + c2)                  [4096,256]
//   3. GEMM3: XH = X0 @ Wp^T                                             [4096,256]
//   4. a_src/a_tgt per node/head
//   5. adjacency (u8 OR int32/f32 layout, probed at runtime) -> nbr lists
//   6. per-node sparse softmax attention + residual + LayerNorm -> XLN
//   7. BN3 stats -> GEMM4
//   8. BN4 stats -> GEMM5
//   9. logits
// ---------------------------------------------------------------------------

#define NNODES 4096
#define CAP 128          // max neighbor capacity (Poisson(32) tail << 128)

__device__ __forceinline__ float gelu_f(float x) {
    return 0.5f * x * (1.0f + erff(x * 0.70710678118654752f));
}

// ---------------- adjacency layout probe -----------------------------------
// Self-loops guarantee the diagonal is set. Test both layout hypotheses:
//   u8 layout:  byte[i*4097]  is diag element -> nonzero for all 64 probes
//   i32 layout: word[i*4097]  is diag element -> nonzero for all 64 probes
// Under the WRONG hypothesis the probed location is effectively a random
// ~0.8%-dense bit -> expected popcount ~1-16 of 64. Majority wins.
__global__ __launch_bounds__(64) void probe_adj_kernel(
    const unsigned char* __restrict__ adj, int* __restrict__ flag)
{
    int i = threadIdx.x;                 // 0..63
    bool a = adj[(size_t)i * 4097] != 0;
    bool b = ((const unsigned int*)adj)[(size_t)i * 4097] != 0;
    unsigned long long mA = __ballot(a);
    unsigned long long mB = __ballot(b);
    if (i == 0)
        *flag = (__popcll(mA) >= __popcll(mB)) ? 0 : 1;   // 0 = u8, 1 = 4-byte
}

// ---------------- column stats (BatchNorm batch statistics) ----------------
template<int CPT>
__global__ __launch_bounds__(256) void colstats_partial(
    const float* __restrict__ X, float* __restrict__ part, int rpb)
{
    const int C = CPT * 256;
    const int r0 = blockIdx.x * rpb;
    const int t = threadIdx.x;
    float s[CPT], q[CPT];
#pragma unroll
    for (int cc = 0; cc < CPT; ++cc) { s[cc] = 0.f; q[cc] = 0.f; }
    for (int r = 0; r < rpb; ++r) {
        const float* row = X + (size_t)(r0 + r) * C;
#pragma unroll
        for (int cc = 0; cc < CPT; ++cc) {
            float v = row[cc * 256 + t];
            s[cc] += v;
            q[cc] += v * v;
        }
    }
#pragma unroll
    for (int cc = 0; cc < CPT; ++cc) {
        int c = cc * 256 + t;
        part[((size_t)blockIdx.x * C + c) * 2 + 0] = s[cc];
        part[((size_t)blockIdx.x * C + c) * 2 + 1] = q[cc];
    }
}

__global__ __launch_bounds__(256) void colstats_final(
    const float* __restrict__ part, const float* __restrict__ g,
    const float* __restrict__ bt, float* __restrict__ scl,
    float* __restrict__ shf, int NB, int C)
{
    int c = blockIdx.x * 256 + threadIdx.x;
    if (c >= C) return;
    float s = 0.f, q = 0.f;
    for (int b = 0; b < NB; ++b) {
        s += part[((size_t)b * C + c) * 2 + 0];
        q += part[((size_t)b * C + c) * 2 + 1];
    }
    float m = s * (1.0f / 4096.0f);
    float v = q * (1.0f / 4096.0f) - m * m;
    float sc = g[c] * rsqrtf(v + 1e-5f);
    scl[c] = sc;
    shf[c] = bt[c] - m * sc;
}

// ---------------- GEMM: C[M,N] = epi( bn(A)[M,K] @ W[N,K]^T + bias ) -------
// 64x64 tile, BK=16, 256 threads, 4x4 per thread.
template<bool BN, bool EPI>
__global__ __launch_bounds__(256) void gemm_kernel(
    const float* __restrict__ A, const float* __restrict__ scl,
    const float* __restrict__ shf, const float* __restrict__ W,
    const float* __restrict__ bias, float* __restrict__ C,
    int M, int N, int K)
{
    __shared__ float As[16][68];
    __shared__ float Bs[16][68];
    const int t = threadIdx.x;
    const int tm = t >> 4, tn = t & 15;
    const int row4 = t >> 2;
    const int kq = (t & 3) << 2;
    const float* Arow = A + (size_t)(blockIdx.y * 64 + row4) * K + kq;
    const float* Wrow = W + (size_t)(blockIdx.x * 64 + row4) * K + kq;
    float acc[4][4];
#pragma unroll
    for (int i = 0; i < 4; ++i)
#pragma unroll
        for (int j = 0; j < 4; ++j) acc[i][j] = 0.f;

    for (int k0 = 0; k0 < K; k0 += 16) {
        float4 av = *(const float4*)(Arow + k0);
        if (BN) {
            float4 s4 = *(const float4*)(scl + k0 + kq);
            float4 f4 = *(const float4*)(shf + k0 + kq);
            av.x = fmaf(av.x, s4.x, f4.x);
            av.y = fmaf(av.y, s4.y, f4.y);
            av.z = fmaf(av.z, s4.z, f4.z);
            av.w = fmaf(av.w, s4.w, f4.w);
        }
        float4 bv = *(const float4*)(Wrow + k0);
        As[kq + 0][row4] = av.x; As[kq + 1][row4] = av.y;
        As[kq + 2][row4] = av.z; As[kq + 3][row4] = av.w;
        Bs[kq + 0][row4] = bv.x; Bs[kq + 1][row4] = bv.y;
        Bs[kq + 2][row4] = bv.z; Bs[kq + 3][row4] = bv.w;
        __syncthreads();
#pragma unroll
        for (int k = 0; k < 16; ++k) {
            float4 a4 = *(const float4*)&As[k][tm << 2];
            float4 b4 = *(const float4*)&Bs[k][tn << 2];
            float aa[4] = {a4.x, a4.y, a4.z, a4.w};
            float bb[4] = {b4.x, b4.y, b4.z, b4.w};
#pragma unroll
            for (int i = 0; i < 4; ++i)
#pragma unroll
                for (int j = 0; j < 4; ++j)
                    acc[i][j] = fmaf(aa[i], bb[j], acc[i][j]);
        }
        __syncthreads();
    }
    const int orow = blockIdx.y * 64 + (tm << 2);
    const int ocol = blockIdx.x * 64 + (tn << 2);
#pragma unroll
    for (int i = 0; i < 4; ++i) {
        float o[4];
#pragma unroll
        for (int j = 0; j < 4; ++j) {
            float c = acc[i][j];
            if (EPI) c = gelu_f(c + bias[ocol + j]);
            o[j] = c;
        }
        float4 ov = {o[0], o[1], o[2], o[3]};
        *(float4*)&C[(size_t)(orow + i) * N + ocol] = ov;
    }
}

// ---------------- a_src / a_tgt --------------------------------------------
__global__ __launch_bounds__(256) void asrc_atgt_kernel(
    const float* __restrict__ xh, const float* __restrict__ Wa,
    float* __restrict__ asrc, float* __restrict__ atgt)
{
    int node = (blockIdx.x * 256 + threadIdx.x) >> 6;
    int lane = threadIdx.x & 63;
    const float* row = xh + (size_t)node * 256;
    float ws = Wa[lane], wt = Wa[64 + lane];
    float s[4], tt[4];
#pragma unroll
    for (int h = 0; h < 4; ++h) {
        float v = row[h * 64 + lane];
        s[h] = v * ws;
        tt[h] = v * wt;
    }
#pragma unroll
    for (int off = 32; off > 0; off >>= 1) {
#pragma unroll
        for (int h = 0; h < 4; ++h) {
            s[h] += __shfl_down(s[h], off);
            tt[h] += __shfl_down(tt[h], off);
        }
    }
    if (lane == 0) {
#pragma unroll
        for (int h = 0; h < 4; ++h) {
            asrc[node * 4 + h] = s[h];
            atgt[node * 4 + h] = tt[h];
        }
    }
}

// ---------------- adjacency -> neighbor lists (layout-adaptive) ------------
__global__ __launch_bounds__(256) void build_nbr_kernel(
    const unsigned char* __restrict__ adj, const int* __restrict__ flag,
    int* __restrict__ nbr, int* __restrict__ deg)
{
    int i = (blockIdx.x * 256 + threadIdx.x) >> 6;   // one wave per row
    int lane = threadIdx.x & 63;
    int cnt = 0;
    if (*flag == 0) {
        // u8 layout: 4096 bytes per row
        const unsigned int* row = (const unsigned int*)(adj + (size_t)i * NNODES);
        for (int it = 0; it < NNODES / 256; ++it) {
            unsigned int v = row[it * 64 + lane];
#pragma unroll
            for (int b = 0; b < 4; ++b) {
                bool on = ((v >> (8 * b)) & 0xffu) != 0;
                unsigned long long m = __ballot(on);
                int pre = __popcll(m & ((1ull << lane) - 1ull));
                if (on && cnt + pre < CAP)
                    nbr[(size_t)i * CAP + cnt + pre] = it * 256 + lane * 4 + b;
                cnt += __popcll(m);
            }
        }
    } else {
        // 4-byte layout (int32 or float32 bool): 4096 words per row
        const unsigned int* row = (const unsigned int*)adj + (size_t)i * NNODES;
        for (int it = 0; it < NNODES / 64; ++it) {
            unsigned int v = row[it * 64 + lane];
            bool on = v != 0;
            unsigned long long m = __ballot(on);
            int pre = __popcll(m & ((1ull << lane) - 1ull));
            if (on && cnt + pre < CAP)
                nbr[(size_t)i * CAP + cnt + pre] = it * 64 + lane;
            cnt += __popcll(m);
        }
    }
    if (lane == 0) deg[i] = cnt < CAP ? cnt : CAP;
}

// ---------------- attention + residual + LayerNorm -------------------------
__global__ __launch_bounds__(256) void attn_ln_kernel(
    const float* __restrict__ xh, const float* __restrict__ x0,
    const float* __restrict__ asrc, const float* __restrict__ atgt,
    const int* __restrict__ nbr, const int* __restrict__ deg_,
    const float* __restrict__ ln_g, const float* __restrict__ ln_b,
    float* __restrict__ xln)
{
    __shared__ float att[CAP * 4];
    __shared__ int nb[CAP];
    __shared__ float red[8];
    const int i = blockIdx.x;
    const int t = threadIdx.x;
    const int dg = deg_[i];

    for (int k = t; k < dg; k += 256) nb[k] = nbr[(size_t)i * CAP + k];
    __syncthreads();

    for (int idx = t; idx < dg * 4; idx += 256) {
        int k = idx >> 2, h = idx & 3;
        float e = asrc[nb[k] * 4 + h] + atgt[i * 4 + h];
        att[idx] = e > 0.f ? e : 0.2f * e;
    }
    __syncthreads();

    const int wv = t >> 6, lane = t & 63;
    {
        const int h = wv;
        float m = -1e30f;
        for (int k = lane; k < dg; k += 64) m = fmaxf(m, att[k * 4 + h]);
#pragma unroll
        for (int off = 32; off > 0; off >>= 1) m = fmaxf(m, __shfl_xor(m, off));
        float s = 0.f;
        for (int k = lane; k < dg; k += 64) s += expf(att[k * 4 + h] - m);
#pragma unroll
        for (int off = 32; off > 0; off >>= 1) s += __shfl_xor(s, off);
        float inv = 1.0f / s;
        for (int k = lane; k < dg; k += 64)
            att[k * 4 + h] = expf(att[k * 4 + h] - m) * inv;
    }
    __syncthreads();

    const int h = t >> 6;
    float acc = 0.f;
    for (int k = 0; k < dg; ++k)
        acc = fmaf(att[k * 4 + h], xh[(size_t)nb[k] * 256 + t], acc);

    float v = x0[(size_t)i * 256 + t] + acc;
    float s = v, q = v * v;
#pragma unroll
    for (int off = 32; off > 0; off >>= 1) {
        s += __shfl_xor(s, off);
        q += __shfl_xor(q, off);
    }
    if (lane == 0) { red[wv] = s; red[4 + wv] = q; }
    __syncthreads();
    float S = red[0] + red[1] + red[2] + red[3];
    float Q = red[4] + red[5] + red[6] + red[7];
    float mu = S * (1.0f / 256.0f);
    float var = Q * (1.0f / 256.0f) - mu * mu;
    float y = (v - mu) * rsqrtf(var + 1e-5f) * ln_g[t] + ln_b[t];
    xln[(size_t)i * 256 + t] = y;
}

// ---------------- gather + logits ------------------------------------------
__global__ __launch_bounds__(256) void logits_kernel(
    const float* __restrict__ xf, const int* __restrict__ idxs,
    const float* __restrict__ Wl, const float* __restrict__ cl,
    float* __restrict__ out)
{
    __shared__ float rows[8][260];
    const int b = blockIdx.x, t = threadIdx.x;
    for (int e = t; e < 8 * 256; e += 256) {
        int r = e >> 8, c = e & 255;
        rows[r][c] = xf[(size_t)idxs[b * 8 + r] * 256 + c];
    }
    __syncthreads();
    for (int o = t; o < 8 * 40; o += 256) {
        int r = o / 40, c = o - r * 40;
        const float* w = Wl + (size_t)c * 256;
        float acc = cl[c];
        for (int k = 0; k < 256; ++k) acc = fmaf(rows[r][k], w[k], acc);
        out[(size_t)(b * 8 + r) * 40 + c] = acc;
    }
}

// ---------------------------------------------------------------------------
extern "C" void kernel_launch(void* const* d_in, const int* in_sizes, int n_in,
                              void* d_out, int out_size, void* d_ws, size_t ws_size,
                              hipStream_t stream)
{
    const float* nf      = (const float*)d_in[0];
    const float* pre_g1  = (const float*)d_in[1];
    const float* pre_b1  = (const float*)d_in[2];
    const float* pre_W1  = (const float*)d_in[3];
    const float* pre_c1  = (const float*)d_in[4];
    const float* pre_g2  = (const float*)d_in[5];
    const float* pre_b2  = (const float*)d_in[6];
    const float* pre_W2  = (const float*)d_in[7];
    const float* pre_c2  = (const float*)d_in[8];
    const float* Wp      = (const float*)d_in[9];
    const float* Wa      = (const float*)d_in[10];
    const float* ln_g    = (const float*)d_in[11];
    const float* ln_b    = (const float*)d_in[12];
    const float* post_g1 = (const float*)d_in[13];
    const float* post_b1 = (const float*)d_in[14];
    const float* post_W1 = (const float*)d_in[15];
    const float* post_c1 = (const float*)d_in[16];
    const float* post_g2 = (const float*)d_in[17];
    const float* post_b2 = (const float*)d_in[18];
    const float* post_W2 = (const float*)d_in[19];
    const float* post_c2 = (const float*)d_in[20];
    const float* Wl      = (const float*)d_in[21];
    const float* cl      = (const float*)d_in[22];
    const unsigned char* adj = (const unsigned char*)d_in[23];
    const int* idxs      = (const int*)d_in[24];
    float* out = (float*)d_out;

    size_t off = 0;
    char* base = (char*)d_ws;
    auto carve = [&](size_t bytes) {
        void* p = base + off;
        off += (bytes + 255) & ~(size_t)255;
        return p;
    };
    float* Y    = (float*)carve((size_t)4096 * 1024 * 4);
    float* X0   = (float*)carve((size_t)4096 * 256 * 4);
    float* XH   = (float*)carve((size_t)4096 * 256 * 4);
    float* XLN  = (float*)carve((size_t)4096 * 256 * 4);
    float* XF   = (float*)carve((size_t)4096 * 256 * 4);
    int*   NBR  = (int*)  carve((size_t)4096 * CAP * 4);
    int*   DEG  = (int*)  carve((size_t)4096 * 4);
    float* ASRC = (float*)carve((size_t)4096 * 4 * 4);
    float* ATGT = (float*)carve((size_t)4096 * 4 * 4);
    float* PART = (float*)carve((size_t)128 * 1024 * 2 * 4);
    float* SCL1 = (float*)carve(512 * 4);
    float* SHF1 = (float*)carve(512 * 4);
    float* SCL2 = (float*)carve(1024 * 4);
    float* SHF2 = (float*)carve(1024 * 4);
    float* SCL3 = (float*)carve(256 * 4);
    float* SHF3 = (float*)carve(256 * 4);
    float* SCL4 = (float*)carve(1024 * 4);
    float* SHF4 = (float*)carve(1024 * 4);
    int*   FLAG = (int*)  carve(256);
    (void)ws_size; (void)n_in; (void)in_sizes; (void)out_size;

    const int NB = 128, RPB = 4096 / 128;

    // adjacency layout probe (independent of everything else; run first)
    probe_adj_kernel<<<1, 64, 0, stream>>>(adj, FLAG);

    // 1) BN1 stats + GEMM1
    colstats_partial<2><<<NB, 256, 0, stream>>>(nf, PART, RPB);
    colstats_final<<<2, 256, 0, stream>>>(PART, pre_g1, pre_b1, SCL1, SHF1, NB, 512);
    gemm_kernel<true, true><<<dim3(1024 / 64, 4096 / 64), 256, 0, stream>>>(
        nf, SCL1, SHF1, pre_W1, pre_c1, Y, 4096, 1024, 512);

    // 2) BN2 stats + GEMM2
    colstats_partial<4><<<NB, 256, 0, stream>>>(Y, PART, RPB);
    colstats_final<<<4, 256, 0, stream>>>(PART, pre_g2, pre_b2, SCL2, SHF2, NB, 1024);
    gemm_kernel<true, true><<<dim3(256 / 64, 4096 / 64), 256, 0, stream>>>(
        Y, SCL2, SHF2, pre_W2, pre_c2, X0, 4096, 256, 1024);

    // 3) GEMM3: XH = X0 @ Wp^T
    gemm_kernel<false, false><<<dim3(256 / 64, 4096 / 64), 256, 0, stream>>>(
        X0, nullptr, nullptr, Wp, nullptr, XH, 4096, 256, 256);

    // 4) attention scalars
    asrc_atgt_kernel<<<1024, 256, 0, stream>>>(XH, Wa, ASRC, ATGT);

    // 5) neighbor lists (layout-adaptive)
    build_nbr_kernel<<<1024, 256, 0, stream>>>(adj, FLAG, NBR, DEG);

    // 6) attention + residual + LayerNorm
    attn_ln_kernel<<<4096, 256, 0, stream>>>(XH, X0, ASRC, ATGT, NBR, DEG,
                                             ln_g, ln_b, XLN);

    // 7) BN3 stats + GEMM4
    colstats_partial<1><<<NB, 256, 0, stream>>>(XLN, PART, RPB);
    colstats_final<<<1, 256, 0, stream>>>(PART, post_g1, post_b1, SCL3, SHF3, NB, 256);
    gemm_kernel<true, true><<<dim3(1024 / 64, 4096 / 64), 256, 0, stream>>>(
        XLN, SCL3, SHF3, post_W1, post_c1, Y, 4096, 1024, 256);

    // 8) BN4 stats + GEMM5
    colstats_partial<4><<<NB, 256, 0, stream>>>(Y, PART, RPB);
    colstats_final<<<4, 256, 0, stream>>>(PART, post_g2, post_b2, SCL4, SHF4, NB, 1024);
    gemm_kernel<true, true><<<dim3(256 / 64, 4096 / 64), 256, 0, stream>>>(
        Y, SCL4, SHF4, post_W2, post_c2, XF, 4096, 256, 1024);

    // 9) gather + logits
    logits_kernel<<<8192 / 8, 256, 0, stream>>>(XF, idxs, Wl, cl, out);
}

// Round 4
// 333.214 us; speedup vs baseline: 1.4756x; 1.4756x over previous
//
#include <hip/hip_runtime.h>
#include <hip/hip_bf16.h>

// ---------------------------------------------------------------------------
// GANClassifier forward, round 3: bf16 MFMA GEMMs + folded BatchNorm.
//   bn(X) @ W^T + c  ==  X @ (W*scl)^T + (c + W@shf)   -> fold BN into weights
//   All 5 GEMMs: mfma_f32_16x16x32_bf16, 64x64 tile, BK=64, m97 2-phase,
//   global_load_lds(16B) with pre-swizzled source + swizzled ds_read (rule #21).
// ---------------------------------------------------------------------------

#define NNODES 4096
#define CAP 128

typedef unsigned short u16;
typedef __attribute__((ext_vector_type(8))) short bf16x8;
typedef __attribute__((ext_vector_type(4))) float f32x4;

__device__ __forceinline__ float gelu_f(float x) {
    return 0.5f * x * (1.0f + erff(x * 0.70710678118654752f));
}
__device__ __forceinline__ u16 f2bf(float x) {
    union { float f; unsigned u; } v; v.f = x;
    unsigned r = v.u + 0x7fff + ((v.u >> 16) & 1);
    return (u16)(r >> 16);
}
__device__ __forceinline__ float bf2f(u16 b) {
    return __uint_as_float(((unsigned)b) << 16);
}
__device__ __forceinline__ void gload16(const void* g, void* l) {
    __builtin_amdgcn_global_load_lds(
        (const __attribute__((address_space(1))) unsigned int*)g,
        (__attribute__((address_space(3))) unsigned int*)l, 16, 0, 0);
}

// ---------------- adjacency layout probe -----------------------------------
__global__ __launch_bounds__(64) void probe_adj_kernel(
    const unsigned char* __restrict__ adj, int* __restrict__ flag)
{
    int i = threadIdx.x;
    bool a = adj[(size_t)i * 4097] != 0;
    bool b = ((const unsigned int*)adj)[(size_t)i * 4097] != 0;
    unsigned long long mA = __ballot(a);
    unsigned long long mB = __ballot(b);
    if (i == 0)
        *flag = (__popcll(mA) >= __popcll(mB)) ? 0 : 1;   // 0 = u8, 1 = 4-byte
}

// ---------------- column stats (fp32 input) --------------------------------
template<int CPT>
__global__ __launch_bounds__(256) void colstats_partial(
    const float* __restrict__ X, float* __restrict__ part, int rpb)
{
    const int C = CPT * 256;
    const int r0 = blockIdx.x * rpb;
    const int t = threadIdx.x;
    float s[CPT], q[CPT];
#pragma unroll
    for (int cc = 0; cc < CPT; ++cc) { s[cc] = 0.f; q[cc] = 0.f; }
    for (int r = 0; r < rpb; ++r) {
        const float* row = X + (size_t)(r0 + r) * C;
#pragma unroll
        for (int cc = 0; cc < CPT; ++cc) {
            float v = row[cc * 256 + t];
            s[cc] += v; q[cc] += v * v;
        }
    }
#pragma unroll
    for (int cc = 0; cc < CPT; ++cc) {
        int c = cc * 256 + t;
        part[((size_t)blockIdx.x * C + c) * 2 + 0] = s[cc];
        part[((size_t)blockIdx.x * C + c) * 2 + 1] = q[cc];
    }
}

// ---------------- column stats (bf16 input) --------------------------------
template<int CPT>
__global__ __launch_bounds__(256) void colstats_partial_b16(
    const u16* __restrict__ X, float* __restrict__ part, int rpb)
{
    const int C = CPT * 256;
    const int r0 = blockIdx.x * rpb;
    const int t = threadIdx.x;
    float s[CPT], q[CPT];
#pragma unroll
    for (int cc = 0; cc < CPT; ++cc) { s[cc] = 0.f; q[cc] = 0.f; }
    for (int r = 0; r < rpb; ++r) {
        const u16* row = X + (size_t)(r0 + r) * C;
#pragma unroll
        for (int cc = 0; cc < CPT; ++cc) {
            float v = bf2f(row[cc * 256 + t]);
            s[cc] += v; q[cc] += v * v;
        }
    }
#pragma unroll
    for (int cc = 0; cc < CPT; ++cc) {
        int c = cc * 256 + t;
        part[((size_t)blockIdx.x * C + c) * 2 + 0] = s[cc];
        part[((size_t)blockIdx.x * C + c) * 2 + 1] = q[cc];
    }
}

__global__ __launch_bounds__(256) void colstats_final(
    const float* __restrict__ part, const float* __restrict__ g,
    const float* __restrict__ bt, float* __restrict__ scl,
    float* __restrict__ shf, int NB, int C)
{
    int c = blockIdx.x * 256 + threadIdx.x;
    if (c >= C) return;
    float s = 0.f, q = 0.f;
    for (int b = 0; b < NB; ++b) {
        s += part[((size_t)b * C + c) * 2 + 0];
        q += part[((size_t)b * C + c) * 2 + 1];
    }
    float m = s * (1.0f / 4096.0f);
    float v = q * (1.0f / 4096.0f) - m * m;
    float sc = g[c] * rsqrtf(v + 1e-5f);
    scl[c] = sc;
    shf[c] = bt[c] - m * sc;
}

// ---------------- fp32 -> bf16 conversion ----------------------------------
__global__ __launch_bounds__(256) void cvt_bf16_kernel(
    const float* __restrict__ x, u16* __restrict__ o)
{
    int i = (blockIdx.x * 256 + threadIdx.x) * 4;
    float4 v = *(const float4*)(x + i);
    ushort4 r;
    r.x = f2bf(v.x); r.y = f2bf(v.y); r.z = f2bf(v.z); r.w = f2bf(v.w);
    *(ushort4*)(o + i) = r;
}

// ---------------- fold BN into weights: W16 = bf16(W*scl), b' = c + W@shf --
__global__ __launch_bounds__(256) void foldw_kernel(
    const float* __restrict__ W, const float* __restrict__ scl,
    const float* __restrict__ shf, const float* __restrict__ bias,
    u16* __restrict__ W16, float* __restrict__ bout, int K)
{
    __shared__ float red[4];
    const int n = blockIdx.x, t = threadIdx.x;
    const float* w = W + (size_t)n * K;
    u16* o = W16 + (size_t)n * K;
    float part = 0.f;
    for (int k = t; k < K; k += 256) {
        float wv = w[k];
        float s = scl ? scl[k] : 1.f;
        float f = shf ? shf[k] : 0.f;
        o[k] = f2bf(wv * s);
        part += wv * f;
    }
    int lane = t & 63, wv_ = t >> 6;
#pragma unroll
    for (int off = 32; off > 0; off >>= 1) part += __shfl_down(part, off);
    if (lane == 0) red[wv_] = part;
    __syncthreads();
    if (t == 0)
        bout[n] = (bias ? bias[n] : 0.f) + red[0] + red[1] + red[2] + red[3];
}

// ---------------- bf16 MFMA GEMM: C = epi(A @ W^T + bias) ------------------
// A[M,K], W[N,K] bf16 row-major. 64x64 tile, BK=64, 256 thr = 4 waves (2x2),
// each wave 32x32 out = 2x2 frags of 16x16. m97 2-phase + st-swizzle.
template<bool EPI, bool S32, bool S16>
__global__ __launch_bounds__(256) void mfma_gemm(
    const u16* __restrict__ A, const u16* __restrict__ W,
    const float* __restrict__ bias, float* __restrict__ C32,
    u16* __restrict__ C16, int M, int N, int K)
{
    __shared__ u16 As[64 * 64];
    __shared__ u16 Bs[64 * 64];
    const int t = threadIdx.x;
    const int lane = t & 63, wv = t >> 6;
    const int wm = (wv >> 1) * 32, wn = (wv & 1) * 32;
    const int tile_m = blockIdx.y * 64, tile_n = blockIdx.x * 64;

    f32x4 acc[2][2];
#pragma unroll
    for (int i = 0; i < 2; ++i)
#pragma unroll
        for (int j = 0; j < 2; ++j)
#pragma unroll
            for (int e = 0; e < 4; ++e) acc[i][j][e] = 0.f;

    // staging geometry: flat chunk f = i*256+t; row=f>>3, dst chunk=f&7,
    // src chunk = dst ^ (row&7)  (inverse-swizzled source, linear LDS dest)
    int srow[2], soff[2];
#pragma unroll
    for (int i = 0; i < 2; ++i) {
        int f = i * 256 + t;
        srow[i] = f >> 3;
        soff[i] = ((f & 7) ^ (srow[i] & 7)) * 8;     // elements
    }
    char* ldsA0 = (char*)As + (t >> 6) * 1024;        // wave-uniform base
    char* ldsB0 = (char*)Bs + (t >> 6) * 1024;
    const int frow_a0 = wm + (lane & 15);             // frag rows (mi adds 16)
    const int frow_b0 = wn + (lane & 15);
    const int fk = (lane >> 4) * 16;                  // byte offset within 64B half

    const int NT = K >> 6;
    for (int kt = 0; kt < NT; ++kt) {
#pragma unroll
        for (int i = 0; i < 2; ++i) {
            gload16(A + (size_t)(tile_m + srow[i]) * K + kt * 64 + soff[i],
                    ldsA0 + i * 4096);
            gload16(W + (size_t)(tile_n + srow[i]) * K + kt * 64 + soff[i],
                    ldsB0 + i * 4096);
        }
        __syncthreads();   // vmcnt(0): tile staged
#pragma unroll
        for (int kk = 0; kk < 2; ++kk) {
            bf16x8 a[2], b[2];
#pragma unroll
            for (int mi = 0; mi < 2; ++mi) {
                int r = frow_a0 + mi * 16;
                a[mi] = *(const bf16x8*)((const char*)As + r * 128 +
                        ((kk * 64 + fk) ^ ((r & 7) << 4)));
            }
#pragma unroll
            for (int ni = 0; ni < 2; ++ni) {
                int r = frow_b0 + ni * 16;
                b[ni] = *(const bf16x8*)((const char*)Bs + r * 128 +
                        ((kk * 64 + fk) ^ ((r & 7) << 4)));
            }
#pragma unroll
            for (int mi = 0; mi < 2; ++mi)
#pragma unroll
                for (int ni = 0; ni < 2; ++ni)
                    acc[mi][ni] = __builtin_amdgcn_mfma_f32_16x16x32_bf16(
                        a[mi], b[ni], acc[mi][ni], 0, 0, 0);
        }
        __syncthreads();   // all waves done reading before next stage
    }

    // epilogue: D col = lane&15, row = (lane>>4)*4 + e (HW-verified m89/m91)
#pragma unroll
    for (int mi = 0; mi < 2; ++mi) {
#pragma unroll
        for (int ni = 0; ni < 2; ++ni) {
            int col = tile_n + wn + ni * 16 + (lane & 15);
            float bs = 0.f;
            if (EPI) bs = bias[col];
#pragma unroll
            for (int e = 0; e < 4; ++e) {
                int row = tile_m + wm + mi * 16 + ((lane >> 4) << 2) + e;
                float c = acc[mi][ni][e];
                if (EPI) c = gelu_f(c + bs);
                if (S32) C32[(size_t)row * N + col] = c;
                if (S16) C16[(size_t)row * N + col] = f2bf(c);
            }
        }
    }
}

// ---------------- a_src / a_tgt --------------------------------------------
__global__ __launch_bounds__(256) void asrc_atgt_kernel(
    const float* __restrict__ xh, const float* __restrict__ Wa,
    float* __restrict__ asrc, float* __restrict__ atgt)
{
    int node = (blockIdx.x * 256 + threadIdx.x) >> 6;
    int lane = threadIdx.x & 63;
    const float* row = xh + (size_t)node * 256;
    float ws = Wa[lane], wt = Wa[64 + lane];
    float s[4], tt[4];
#pragma unroll
    for (int h = 0; h < 4; ++h) {
        float v = row[h * 64 + lane];
        s[h] = v * ws; tt[h] = v * wt;
    }
#pragma unroll
    for (int off = 32; off > 0; off >>= 1) {
#pragma unroll
        for (int h = 0; h < 4; ++h) {
            s[h] += __shfl_down(s[h], off);
            tt[h] += __shfl_down(tt[h], off);
        }
    }
    if (lane == 0) {
#pragma unroll
        for (int h = 0; h < 4; ++h) {
            asrc[node * 4 + h] = s[h];
            atgt[node * 4 + h] = tt[h];
        }
    }
}

// ---------------- adjacency -> neighbor lists (layout-adaptive) ------------
__global__ __launch_bounds__(256) void build_nbr_kernel(
    const unsigned char* __restrict__ adj, const int* __restrict__ flag,
    int* __restrict__ nbr, int* __restrict__ deg)
{
    int i = (blockIdx.x * 256 + threadIdx.x) >> 6;
    int lane = threadIdx.x & 63;
    int cnt = 0;
    if (*flag == 0) {
        const unsigned int* row = (const unsigned int*)(adj + (size_t)i * NNODES);
        for (int it = 0; it < NNODES / 256; ++it) {
            unsigned int v = row[it * 64 + lane];
#pragma unroll
            for (int b = 0; b < 4; ++b) {
                bool on = ((v >> (8 * b)) & 0xffu) != 0;
                unsigned long long m = __ballot(on);
                int pre = __popcll(m & ((1ull << lane) - 1ull));
                if (on && cnt + pre < CAP)
                    nbr[(size_t)i * CAP + cnt + pre] = it * 256 + lane * 4 + b;
                cnt += __popcll(m);
            }
        }
    } else {
        const unsigned int* row = (const unsigned int*)adj + (size_t)i * NNODES;
        for (int it = 0; it < NNODES / 64; ++it) {
            unsigned int v = row[it * 64 + lane];
            bool on = v != 0;
            unsigned long long m = __ballot(on);
            int pre = __popcll(m & ((1ull << lane) - 1ull));
            if (on && cnt + pre < CAP)
                nbr[(size_t)i * CAP + cnt + pre] = it * 64 + lane;
            cnt += __popcll(m);
        }
    }
    if (lane == 0) deg[i] = cnt < CAP ? cnt : CAP;
}

// ---------------- attention + residual + LayerNorm -------------------------
__global__ __launch_bounds__(256) void attn_ln_kernel(
    const float* __restrict__ xh, const float* __restrict__ x0,
    const float* __restrict__ asrc, const float* __restrict__ atgt,
    const int* __restrict__ nbr, const int* __restrict__ deg_,
    const float* __restrict__ ln_g, const float* __restrict__ ln_b,
    float* __restrict__ xln, u16* __restrict__ xln16)
{
    __shared__ float att[CAP * 4];
    __shared__ int nb[CAP];
    __shared__ float red[8];
    const int i = blockIdx.x;
    const int t = threadIdx.x;
    const int dg = deg_[i];

    for (int k = t; k < dg; k += 256) nb[k] = nbr[(size_t)i * CAP + k];
    __syncthreads();

    for (int idx = t; idx < dg * 4; idx += 256) {
        int k = idx >> 2, h = idx & 3;
        float e = asrc[nb[k] * 4 + h] + atgt[i * 4 + h];
        att[idx] = e > 0.f ? e : 0.2f * e;
    }
    __syncthreads();

    const int wv = t >> 6, lane = t & 63;
    {
        const int h = wv;
        float m = -1e30f;
        for (int k = lane; k < dg; k += 64) m = fmaxf(m, att[k * 4 + h]);
#pragma unroll
        for (int off = 32; off > 0; off >>= 1) m = fmaxf(m, __shfl_xor(m, off));
        float s = 0.f;
        for (int k = lane; k < dg; k += 64) s += expf(att[k * 4 + h] - m);
#pragma unroll
        for (int off = 32; off > 0; off >>= 1) s += __shfl_xor(s, off);
        float inv = 1.0f / s;
        for (int k = lane; k < dg; k += 64)
            att[k * 4 + h] = expf(att[k * 4 + h] - m) * inv;
    }
    __syncthreads();

    const int h = t >> 6;
    float acc = 0.f;
    for (int k = 0; k < dg; ++k)
        acc = fmaf(att[k * 4 + h], xh[(size_t)nb[k] * 256 + t], acc);

    float v = x0[(size_t)i * 256 + t] + acc;
    float s = v, q = v * v;
#pragma unroll
    for (int off = 32; off > 0; off >>= 1) {
        s += __shfl_xor(s, off);
        q += __shfl_xor(q, off);
    }
    if (lane == 0) { red[wv] = s; red[4 + wv] = q; }
    __syncthreads();
    float S = red[0] + red[1] + red[2] + red[3];
    float Q = red[4] + red[5] + red[6] + red[7];
    float mu = S * (1.0f / 256.0f);
    float var = Q * (1.0f / 256.0f) - mu * mu;
    float y = (v - mu) * rsqrtf(var + 1e-5f) * ln_g[t] + ln_b[t];
    xln[(size_t)i * 256 + t] = y;
    xln16[(size_t)i * 256 + t] = f2bf(y);
}

// ---------------- gather + logits ------------------------------------------
__global__ __launch_bounds__(256) void logits_kernel(
    const float* __restrict__ xf, const int* __restrict__ idxs,
    const float* __restrict__ Wl, const float* __restrict__ cl,
    float* __restrict__ out)
{
    __shared__ float rows[8][260];
    const int b = blockIdx.x, t = threadIdx.x;
    for (int e = t; e < 8 * 256; e += 256) {
        int r = e >> 8, c = e & 255;
        rows[r][c] = xf[(size_t)idxs[b * 8 + r] * 256 + c];
    }
    __syncthreads();
    for (int o = t; o < 8 * 40; o += 256) {
        int r = o / 40, c = o - r * 40;
        const float* w = Wl + (size_t)c * 256;
        float acc = cl[c];
        for (int k = 0; k < 256; ++k) acc = fmaf(rows[r][k], w[k], acc);
        out[(size_t)(b * 8 + r) * 40 + c] = acc;
    }
}

// ---------------------------------------------------------------------------
extern "C" void kernel_launch(void* const* d_in, const int* in_sizes, int n_in,
                              void* d_out, int out_size, void* d_ws, size_t ws_size,
                              hipStream_t stream)
{
    const float* nf      = (const float*)d_in[0];
    const float* pre_g1  = (const float*)d_in[1];
    const float* pre_b1  = (const float*)d_in[2];
    const float* pre_W1  = (const float*)d_in[3];
    const float* pre_c1  = (const float*)d_in[4];
    const float* pre_g2  = (const float*)d_in[5];
    const float* pre_b2  = (const float*)d_in[6];
    const float* pre_W2  = (const float*)d_in[7];
    const float* pre_c2  = (const float*)d_in[8];
    const float* Wp      = (const float*)d_in[9];
    const float* Wa      = (const float*)d_in[10];
    const float* ln_g    = (const float*)d_in[11];
    const float* ln_b    = (const float*)d_in[12];
    const float* post_g1 = (const float*)d_in[13];
    const float* post_b1 = (const float*)d_in[14];
    const float* post_W1 = (const float*)d_in[15];
    const float* post_c1 = (const float*)d_in[16];
    const float* post_g2 = (const float*)d_in[17];
    const float* post_b2 = (const float*)d_in[18];
    const float* post_W2 = (const float*)d_in[19];
    const float* post_c2 = (const float*)d_in[20];
    const float* Wl      = (const float*)d_in[21];
    const float* cl      = (const float*)d_in[22];
    const unsigned char* adj = (const unsigned char*)d_in[23];
    const int* idxs      = (const int*)d_in[24];
    float* out = (float*)d_out;

    size_t off = 0;
    char* base = (char*)d_ws;
    auto carve = [&](size_t bytes) {
        void* p = base + off;
        off += (bytes + 255) & ~(size_t)255;
        return p;
    };
    u16*   Y16   = (u16*)  carve((size_t)4096 * 1024 * 2);  // 8 MB (GEMM1 & 4 out)
    u16*   NF16  = (u16*)  carve((size_t)4096 * 512 * 2);   // 4 MB
    float* X032  = (float*)carve((size_t)4096 * 256 * 4);   // 4 MB
    u16*   X016  = (u16*)  carve((size_t)4096 * 256 * 2);   // 2 MB
    float* XH32  = (float*)carve((size_t)4096 * 256 * 4);   // 4 MB
    float* XLN32 = (float*)carve((size_t)4096 * 256 * 4);   // 4 MB
    u16*   XLN16 = (u16*)  carve((size_t)4096 * 256 * 2);   // 2 MB
    float* XF32  = (float*)carve((size_t)4096 * 256 * 4);   // 4 MB
    u16*   W1_16 = (u16*)  carve((size_t)1024 * 512 * 2);
    u16*   W2_16 = (u16*)  carve((size_t)256 * 1024 * 2);
    u16*   Wp16  = (u16*)  carve((size_t)256 * 256 * 2);
    u16*   W3_16 = (u16*)  carve((size_t)1024 * 256 * 2);
    u16*   W4_16 = (u16*)  carve((size_t)256 * 1024 * 2);
    float* B1    = (float*)carve(1024 * 4);
    float* B2    = (float*)carve(256 * 4);
    float* BP    = (float*)carve(256 * 4);
    float* B3    = (float*)carve(1024 * 4);
    float* B4    = (float*)carve(256 * 4);
    int*   NBR   = (int*)  carve((size_t)4096 * CAP * 4);   // 2 MB
    int*   DEG   = (int*)  carve((size_t)4096 * 4);
    float* ASRC  = (float*)carve((size_t)4096 * 4 * 4);
    float* ATGT  = (float*)carve((size_t)4096 * 4 * 4);
    float* PART  = (float*)carve((size_t)128 * 1024 * 2 * 4); // 1 MB
    float* SCL1  = (float*)carve(512 * 4);
    float* SHF1  = (float*)carve(512 * 4);
    float* SCL2  = (float*)carve(1024 * 4);
    float* SHF2  = (float*)carve(1024 * 4);
    float* SCL3  = (float*)carve(256 * 4);
    float* SHF3  = (float*)carve(256 * 4);
    float* SCL4  = (float*)carve(1024 * 4);
    float* SHF4  = (float*)carve(1024 * 4);
    int*   FLAG  = (int*)  carve(256);
    (void)ws_size; (void)n_in; (void)in_sizes; (void)out_size;

    const int NB = 128, RPB = 4096 / 128;

    probe_adj_kernel<<<1, 64, 0, stream>>>(adj, FLAG);

    // --- stage 1: BN1 fold + GEMM1 (Y = gelu(bn(nf)@W1^T+c1)) -> Y16
    colstats_partial<2><<<NB, 256, 0, stream>>>(nf, PART, RPB);
    colstats_final<<<2, 256, 0, stream>>>(PART, pre_g1, pre_b1, SCL1, SHF1, NB, 512);
    cvt_bf16_kernel<<<(4096 * 512 / 4) / 256, 256, 0, stream>>>(nf, NF16);
    foldw_kernel<<<1024, 256, 0, stream>>>(pre_W1, SCL1, SHF1, pre_c1, W1_16, B1, 512);
    mfma_gemm<true, false, true><<<dim3(16, 64), 256, 0, stream>>>(
        NF16, W1_16, B1, nullptr, Y16, 4096, 1024, 512);

    // --- stage 2: BN2 fold + GEMM2 (X0) -> X032 + X016
    colstats_partial_b16<4><<<NB, 256, 0, stream>>>(Y16, PART, RPB);
    colstats_final<<<4, 256, 0, stream>>>(PART, pre_g2, pre_b2, SCL2, SHF2, NB, 1024);
    foldw_kernel<<<256, 256, 0, stream>>>(pre_W2, SCL2, SHF2, pre_c2, W2_16, B2, 1024);
    mfma_gemm<true, true, true><<<dim3(4, 64), 256, 0, stream>>>(
        Y16, W2_16, B2, X032, X016, 4096, 256, 1024);

    // --- stage 3: GEMM3 (XH = X0 @ Wp^T) -> XH32
    foldw_kernel<<<256, 256, 0, stream>>>(Wp, nullptr, nullptr, nullptr, Wp16, BP, 256);
    mfma_gemm<false, true, false><<<dim3(4, 64), 256, 0, stream>>>(
        X016, Wp16, nullptr, XH32, nullptr, 4096, 256, 256);

    // --- attention
    asrc_atgt_kernel<<<1024, 256, 0, stream>>>(XH32, Wa, ASRC, ATGT);
    build_nbr_kernel<<<1024, 256, 0, stream>>>(adj, FLAG, NBR, DEG);
    attn_ln_kernel<<<4096, 256, 0, stream>>>(XH32, X032, ASRC, ATGT, NBR, DEG,
                                             ln_g, ln_b, XLN32, XLN16);

    // --- stage 4: BN3 fold + GEMM4 -> Y16
    colstats_partial<1><<<NB, 256, 0, stream>>>(XLN32, PART, RPB);
    colstats_final<<<1, 256, 0, stream>>>(PART, post_g1, post_b1, SCL3, SHF3, NB, 256);
    foldw_kernel<<<1024, 256, 0, stream>>>(post_W1, SCL3, SHF3, post_c1, W3_16, B3, 256);
    mfma_gemm<true, false, true><<<dim3(16, 64), 256, 0, stream>>>(
        XLN16, W3_16, B3, nullptr, Y16, 4096, 1024, 256);

    // --- stage 5: BN4 fold + GEMM5 -> XF32
    colstats_partial_b16<4><<<NB, 256, 0, stream>>>(Y16, PART, RPB);
    colstats_final<<<4, 256, 0, stream>>>(PART, post_g2, post_b2, SCL4, SHF4, NB, 1024);
    foldw_kernel<<<256, 256, 0, stream>>>(post_W2, SCL4, SHF4, post_c2, W4_16, B4, 1024);
    mfma_gemm<true, true, false><<<dim3(4, 64), 256, 0, stream>>>(
        Y16, W4_16, B4, XF32, nullptr, 4096, 256, 1024);

    // --- logits
    logits_kernel<<<8192 / 8, 256, 0, stream>>>(XF32, idxs, Wl, cl, out);
}

// Round 5
// 320.537 us; speedup vs baseline: 1.5340x; 1.0395x over previous
//
#include <hip/hip_runtime.h>
#include <hip/hip_bf16.h>

// ---------------------------------------------------------------------------
// GANClassifier forward, round 4: bf16 MFMA GEMMs + folded BN +
// block-per-row neighbor compaction (uint4 loads, per-wave LDS lists).
// ---------------------------------------------------------------------------

#define NNODES 4096
#define CAP 128

typedef unsigned short u16;
typedef __attribute__((ext_vector_type(8))) short bf16x8;
typedef __attribute__((ext_vector_type(4))) float f32x4;

__device__ __forceinline__ float gelu_f(float x) {
    return 0.5f * x * (1.0f + erff(x * 0.70710678118654752f));
}
__device__ __forceinline__ u16 f2bf(float x) {
    union { float f; unsigned u; } v; v.f = x;
    unsigned r = v.u + 0x7fff + ((v.u >> 16) & 1);
    return (u16)(r >> 16);
}
__device__ __forceinline__ float bf2f(u16 b) {
    return __uint_as_float(((unsigned)b) << 16);
}
__device__ __forceinline__ void gload16(const void* g, void* l) {
    __builtin_amdgcn_global_load_lds(
        (const __attribute__((address_space(1))) unsigned int*)g,
        (__attribute__((address_space(3))) unsigned int*)l, 16, 0, 0);
}

// ---------------- adjacency layout probe -----------------------------------
__global__ __launch_bounds__(64) void probe_adj_kernel(
    const unsigned char* __restrict__ adj, int* __restrict__ flag)
{
    int i = threadIdx.x;
    bool a = adj[(size_t)i * 4097] != 0;
    bool b = ((const unsigned int*)adj)[(size_t)i * 4097] != 0;
    unsigned long long mA = __ballot(a);
    unsigned long long mB = __ballot(b);
    if (i == 0)
        *flag = (__popcll(mA) >= __popcll(mB)) ? 0 : 1;   // 0 = u8, 1 = 4-byte
}

// ---------------- column stats (fp32 input, optional bf16 copy-out) --------
template<int CPT, bool CVT>
__global__ __launch_bounds__(256) void colstats_partial(
    const float* __restrict__ X, float* __restrict__ part,
    u16* __restrict__ x16, int rpb)
{
    const int C = CPT * 256;
    const int r0 = blockIdx.x * rpb;
    const int t = threadIdx.x;
    float s[CPT], q[CPT];
#pragma unroll
    for (int cc = 0; cc < CPT; ++cc) { s[cc] = 0.f; q[cc] = 0.f; }
    for (int r = 0; r < rpb; ++r) {
        const float* row = X + (size_t)(r0 + r) * C;
#pragma unroll
        for (int cc = 0; cc < CPT; ++cc) {
            float v = row[cc * 256 + t];
            s[cc] += v; q[cc] += v * v;
            if (CVT) x16[(size_t)(r0 + r) * C + cc * 256 + t] = f2bf(v);
        }
    }
#pragma unroll
    for (int cc = 0; cc < CPT; ++cc) {
        int c = cc * 256 + t;
        part[((size_t)blockIdx.x * C + c) * 2 + 0] = s[cc];
        part[((size_t)blockIdx.x * C + c) * 2 + 1] = q[cc];
    }
}

// ---------------- column stats (bf16 input) --------------------------------
template<int CPT>
__global__ __launch_bounds__(256) void colstats_partial_b16(
    const u16* __restrict__ X, float* __restrict__ part, int rpb)
{
    const int C = CPT * 256;
    const int r0 = blockIdx.x * rpb;
    const int t = threadIdx.x;
    float s[CPT], q[CPT];
#pragma unroll
    for (int cc = 0; cc < CPT; ++cc) { s[cc] = 0.f; q[cc] = 0.f; }
    for (int r = 0; r < rpb; ++r) {
        const u16* row = X + (size_t)(r0 + r) * C;
#pragma unroll
        for (int cc = 0; cc < CPT; ++cc) {
            float v = bf2f(row[cc * 256 + t]);
            s[cc] += v; q[cc] += v * v;
        }
    }
#pragma unroll
    for (int cc = 0; cc < CPT; ++cc) {
        int c = cc * 256 + t;
        part[((size_t)blockIdx.x * C + c) * 2 + 0] = s[cc];
        part[((size_t)blockIdx.x * C + c) * 2 + 1] = q[cc];
    }
}

__global__ __launch_bounds__(256) void colstats_final(
    const float* __restrict__ part, const float* __restrict__ g,
    const float* __restrict__ bt, float* __restrict__ scl,
    float* __restrict__ shf, int NB, int C)
{
    int c = blockIdx.x * 256 + threadIdx.x;
    if (c >= C) return;
    float s = 0.f, q = 0.f;
    for (int b = 0; b < NB; ++b) {
        s += part[((size_t)b * C + c) * 2 + 0];
        q += part[((size_t)b * C + c) * 2 + 1];
    }
    float m = s * (1.0f / 4096.0f);
    float v = q * (1.0f / 4096.0f) - m * m;
    float sc = g[c] * rsqrtf(v + 1e-5f);
    scl[c] = sc;
    shf[c] = bt[c] - m * sc;
}

// ---------------- fold BN into weights: W16 = bf16(W*scl), b' = c + W@shf --
__global__ __launch_bounds__(256) void foldw_kernel(
    const float* __restrict__ W, const float* __restrict__ scl,
    const float* __restrict__ shf, const float* __restrict__ bias,
    u16* __restrict__ W16, float* __restrict__ bout, int K)
{
    __shared__ float red[4];
    const int n = blockIdx.x, t = threadIdx.x;
    const float* w = W + (size_t)n * K;
    u16* o = W16 + (size_t)n * K;
    float part = 0.f;
    for (int k = t; k < K; k += 256) {
        float wv = w[k];
        float s = scl ? scl[k] : 1.f;
        float f = shf ? shf[k] : 0.f;
        o[k] = f2bf(wv * s);
        part += wv * f;
    }
    int lane = t & 63, wv_ = t >> 6;
#pragma unroll
    for (int off = 32; off > 0; off >>= 1) part += __shfl_down(part, off);
    if (lane == 0) red[wv_] = part;
    __syncthreads();
    if (t == 0)
        bout[n] = (bias ? bias[n] : 0.f) + red[0] + red[1] + red[2] + red[3];
}

// ---------------- bf16 MFMA GEMM: C = epi(A @ W^T + bias) ------------------
template<bool EPI, bool S32, bool S16>
__global__ __launch_bounds__(256) void mfma_gemm(
    const u16* __restrict__ A, const u16* __restrict__ W,
    const float* __restrict__ bias, float* __restrict__ C32,
    u16* __restrict__ C16, int M, int N, int K)
{
    __shared__ u16 As[64 * 64];
    __shared__ u16 Bs[64 * 64];
    const int t = threadIdx.x;
    const int lane = t & 63, wv = t >> 6;
    const int wm = (wv >> 1) * 32, wn = (wv & 1) * 32;
    const int tile_m = blockIdx.y * 64, tile_n = blockIdx.x * 64;

    f32x4 acc[2][2];
#pragma unroll
    for (int i = 0; i < 2; ++i)
#pragma unroll
        for (int j = 0; j < 2; ++j)
#pragma unroll
            for (int e = 0; e < 4; ++e) acc[i][j][e] = 0.f;

    int srow[2], soff[2];
#pragma unroll
    for (int i = 0; i < 2; ++i) {
        int f = i * 256 + t;
        srow[i] = f >> 3;
        soff[i] = ((f & 7) ^ (srow[i] & 7)) * 8;
    }
    char* ldsA0 = (char*)As + (t >> 6) * 1024;
    char* ldsB0 = (char*)Bs + (t >> 6) * 1024;
    const int frow_a0 = wm + (lane & 15);
    const int frow_b0 = wn + (lane & 15);
    const int fk = (lane >> 4) * 16;

    const int NT = K >> 6;
    for (int kt = 0; kt < NT; ++kt) {
#pragma unroll
        for (int i = 0; i < 2; ++i) {
            gload16(A + (size_t)(tile_m + srow[i]) * K + kt * 64 + soff[i],
                    ldsA0 + i * 4096);
            gload16(W + (size_t)(tile_n + srow[i]) * K + kt * 64 + soff[i],
                    ldsB0 + i * 4096);
        }
        __syncthreads();
#pragma unroll
        for (int kk = 0; kk < 2; ++kk) {
            bf16x8 a[2], b[2];
#pragma unroll
            for (int mi = 0; mi < 2; ++mi) {
                int r = frow_a0 + mi * 16;
                a[mi] = *(const bf16x8*)((const char*)As + r * 128 +
                        ((kk * 64 + fk) ^ ((r & 7) << 4)));
            }
#pragma unroll
            for (int ni = 0; ni < 2; ++ni) {
                int r = frow_b0 + ni * 16;
                b[ni] = *(const bf16x8*)((const char*)Bs + r * 128 +
                        ((kk * 64 + fk) ^ ((r & 7) << 4)));
            }
#pragma unroll
            for (int mi = 0; mi < 2; ++mi)
#pragma unroll
                for (int ni = 0; ni < 2; ++ni)
                    acc[mi][ni] = __builtin_amdgcn_mfma_f32_16x16x32_bf16(
                        a[mi], b[ni], acc[mi][ni], 0, 0, 0);
        }
        __syncthreads();
    }

#pragma unroll
    for (int mi = 0; mi < 2; ++mi) {
#pragma unroll
        for (int ni = 0; ni < 2; ++ni) {
            int col = tile_n + wn + ni * 16 + (lane & 15);
            float bs = 0.f;
            if (EPI) bs = bias[col];
#pragma unroll
            for (int e = 0; e < 4; ++e) {
                int row = tile_m + wm + mi * 16 + ((lane >> 4) << 2) + e;
                float c = acc[mi][ni][e];
                if (EPI) c = gelu_f(c + bs);
                if (S32) C32[(size_t)row * N + col] = c;
                if (S16) C16[(size_t)row * N + col] = f2bf(c);
            }
        }
    }
}

// ---------------- a_src / a_tgt --------------------------------------------
__global__ __launch_bounds__(256) void asrc_atgt_kernel(
    const float* __restrict__ xh, const float* __restrict__ Wa,
    float* __restrict__ asrc, float* __restrict__ atgt)
{
    int node = (blockIdx.x * 256 + threadIdx.x) >> 6;
    int lane = threadIdx.x & 63;
    const float* row = xh + (size_t)node * 256;
    float ws = Wa[lane], wt = Wa[64 + lane];
    float s[4], tt[4];
#pragma unroll
    for (int h = 0; h < 4; ++h) {
        float v = row[h * 64 + lane];
        s[h] = v * ws; tt[h] = v * wt;
    }
#pragma unroll
    for (int off = 32; off > 0; off >>= 1) {
#pragma unroll
        for (int h = 0; h < 4; ++h) {
            s[h] += __shfl_down(s[h], off);
            tt[h] += __shfl_down(tt[h], off);
        }
    }
    if (lane == 0) {
#pragma unroll
        for (int h = 0; h < 4; ++h) {
            asrc[node * 4 + h] = s[h];
            atgt[node * 4 + h] = tt[h];
        }
    }
}

// ---------------- adjacency -> neighbor lists (block per row) --------------
// 256 thr = 4 waves; each wave compacts a quarter-row into a private LDS
// list (order-agnostic: softmax/weighted-sum are order-invariant), then the
// 4 lists are concatenated. uint4 loads = 1 KB/wave/instr, fully coalesced.
__global__ __launch_bounds__(256) void build_nbr_kernel(
    const unsigned char* __restrict__ adj, const int* __restrict__ flag,
    int* __restrict__ nbr, int* __restrict__ deg)
{
    __shared__ int lists[4][CAP];
    __shared__ int cnts[4];
    const int i = blockIdx.x;
    const int t = threadIdx.x;
    const int wv = t >> 6, lane = t & 63;
    int cnt = 0;

    if (*flag == 1) {
        // 4-byte layout: 4096 words = 1024 uint4 per row
        const uint4* row = (const uint4*)((const unsigned int*)adj + (size_t)i * NNODES);
#pragma unroll
        for (int w = 0; w < 4; ++w) {
            uint4 v = row[w * 256 + t];
            unsigned wd[4] = {v.x, v.y, v.z, v.w};
#pragma unroll
            for (int j = 0; j < 4; ++j) {
                bool on = wd[j] != 0;
                unsigned long long m = __ballot(on);
                int pre = __popcll(m & ((1ull << lane) - 1ull));
                if (on && cnt + pre < CAP)
                    lists[wv][cnt + pre] = (w * 256 + t) * 4 + j;
                cnt += __popcll(m);
            }
        }
    } else {
        // u8 layout: 4096 bytes = 256 uint4 per row, one per thread
        uint4 v = ((const uint4*)(adj + (size_t)i * NNODES))[t];
        unsigned wd[4] = {v.x, v.y, v.z, v.w};
#pragma unroll
        for (int j = 0; j < 4; ++j)
#pragma unroll
            for (int b = 0; b < 4; ++b) {
                bool on = ((wd[j] >> (8 * b)) & 0xffu) != 0;
                unsigned long long m = __ballot(on);
                int pre = __popcll(m & ((1ull << lane) - 1ull));
                if (on && cnt + pre < CAP)
                    lists[wv][cnt + pre] = t * 16 + j * 4 + b;
                cnt += __popcll(m);
            }
    }
    if (lane == 0) cnts[wv] = cnt < CAP ? cnt : CAP;
    __syncthreads();
    int offw = 0;
#pragma unroll
    for (int w2 = 0; w2 < 4; ++w2) if (w2 < wv) offw += cnts[w2];
    int myc = cnts[wv];
    for (int k = lane; k < myc; k += 64) {
        int pos = offw + k;
        if (pos < CAP) nbr[(size_t)i * CAP + pos] = lists[wv][k];
    }
    if (t == 0) {
        int tot = cnts[0] + cnts[1] + cnts[2] + cnts[3];
        deg[i] = tot < CAP ? tot : CAP;
    }
}

// ---------------- attention + residual + LayerNorm -------------------------
__global__ __launch_bounds__(256) void attn_ln_kernel(
    const float* __restrict__ xh, const float* __restrict__ x0,
    const float* __restrict__ asrc, const float* __restrict__ atgt,
    const int* __restrict__ nbr, const int* __restrict__ deg_,
    const float* __restrict__ ln_g, const float* __restrict__ ln_b,
    float* __restrict__ xln, u16* __restrict__ xln16)
{
    __shared__ float att[CAP * 4];
    __shared__ int nb[CAP];
    __shared__ float red[8];
    const int i = blockIdx.x;
    const int t = threadIdx.x;
    const int dg = deg_[i];

    for (int k = t; k < dg; k += 256) nb[k] = nbr[(size_t)i * CAP + k];
    __syncthreads();

    for (int idx = t; idx < dg * 4; idx += 256) {
        int k = idx >> 2, h = idx & 3;
        float e = asrc[nb[k] * 4 + h] + atgt[i * 4 + h];
        att[idx] = e > 0.f ? e : 0.2f * e;
    }
    __syncthreads();

    const int wv = t >> 6, lane = t & 63;
    {
        const int h = wv;
        float m = -1e30f;
        for (int k = lane; k < dg; k += 64) m = fmaxf(m, att[k * 4 + h]);
#pragma unroll
        for (int off = 32; off > 0; off >>= 1) m = fmaxf(m, __shfl_xor(m, off));
        float s = 0.f;
        for (int k = lane; k < dg; k += 64) s += expf(att[k * 4 + h] - m);
#pragma unroll
        for (int off = 32; off > 0; off >>= 1) s += __shfl_xor(s, off);
        float inv = 1.0f / s;
        for (int k = lane; k < dg; k += 64)
            att[k * 4 + h] = expf(att[k * 4 + h] - m) * inv;
    }
    __syncthreads();

    // gather: unroll-4 for memory-level parallelism (4 outstanding loads)
    const int h = t >> 6;
    float acc = 0.f;
    int k = 0;
    for (; k + 4 <= dg; k += 4) {
        float a0 = att[(k + 0) * 4 + h], v0 = xh[(size_t)nb[k + 0] * 256 + t];
        float a1 = att[(k + 1) * 4 + h], v1 = xh[(size_t)nb[k + 1] * 256 + t];
        float a2 = att[(k + 2) * 4 + h], v2 = xh[(size_t)nb[k + 2] * 256 + t];
        float a3 = att[(k + 3) * 4 + h], v3 = xh[(size_t)nb[k + 3] * 256 + t];
        acc = fmaf(a0, v0, acc); acc = fmaf(a1, v1, acc);
        acc = fmaf(a2, v2, acc); acc = fmaf(a3, v3, acc);
    }
    for (; k < dg; ++k)
        acc = fmaf(att[k * 4 + h], xh[(size_t)nb[k] * 256 + t], acc);

    float v = x0[(size_t)i * 256 + t] + acc;
    float s = v, q = v * v;
#pragma unroll
    for (int off = 32; off > 0; off >>= 1) {
        s += __shfl_xor(s, off);
        q += __shfl_xor(q, off);
    }
    if (lane == 0) { red[wv] = s; red[4 + wv] = q; }
    __syncthreads();
    float S = red[0] + red[1] + red[2] + red[3];
    float Q = red[4] + red[5] + red[6] + red[7];
    float mu = S * (1.0f / 256.0f);
    float var = Q * (1.0f / 256.0f) - mu * mu;
    float y = (v - mu) * rsqrtf(var + 1e-5f) * ln_g[t] + ln_b[t];
    xln[(size_t)i * 256 + t] = y;
    xln16[(size_t)i * 256 + t] = f2bf(y);
}

// ---------------- gather + logits ------------------------------------------
__global__ __launch_bounds__(256) void logits_kernel(
    const float* __restrict__ xf, const int* __restrict__ idxs,
    const float* __restrict__ Wl, const float* __restrict__ cl,
    float* __restrict__ out)
{
    __shared__ float rows[8][260];
    const int b = blockIdx.x, t = threadIdx.x;
    for (int e = t; e < 8 * 256; e += 256) {
        int r = e >> 8, c = e & 255;
        rows[r][c] = xf[(size_t)idxs[b * 8 + r] * 256 + c];
    }
    __syncthreads();
    for (int o = t; o < 8 * 40; o += 256) {
        int r = o / 40, c = o - r * 40;
        const float* w = Wl + (size_t)c * 256;
        float acc = cl[c];
        for (int k = 0; k < 256; ++k) acc = fmaf(rows[r][k], w[k], acc);
        out[(size_t)(b * 8 + r) * 40 + c] = acc;
    }
}

// ---------------------------------------------------------------------------
extern "C" void kernel_launch(void* const* d_in, const int* in_sizes, int n_in,
                              void* d_out, int out_size, void* d_ws, size_t ws_size,
                              hipStream_t stream)
{
    const float* nf      = (const float*)d_in[0];
    const float* pre_g1  = (const float*)d_in[1];
    const float* pre_b1  = (const float*)d_in[2];
    const float* pre_W1  = (const float*)d_in[3];
    const float* pre_c1  = (const float*)d_in[4];
    const float* pre_g2  = (const float*)d_in[5];
    const float* pre_b2  = (const float*)d_in[6];
    const float* pre_W2  = (const float*)d_in[7];
    const float* pre_c2  = (const float*)d_in[8];
    const float* Wp      = (const float*)d_in[9];
    const float* Wa      = (const float*)d_in[10];
    const float* ln_g    = (const float*)d_in[11];
    const float* ln_b    = (const float*)d_in[12];
    const float* post_g1 = (const float*)d_in[13];
    const float* post_b1 = (const float*)d_in[14];
    const float* post_W1 = (const float*)d_in[15];
    const float* post_c1 = (const float*)d_in[16];
    const float* post_g2 = (const float*)d_in[17];
    const float* post_b2 = (const float*)d_in[18];
    const float* post_W2 = (const float*)d_in[19];
    const float* post_c2 = (const float*)d_in[20];
    const float* Wl      = (const float*)d_in[21];
    const float* cl      = (const float*)d_in[22];
    const unsigned char* adj = (const unsigned char*)d_in[23];
    const int* idxs      = (const int*)d_in[24];
    float* out = (float*)d_out;

    size_t off = 0;
    char* base = (char*)d_ws;
    auto carve = [&](size_t bytes) {
        void* p = base + off;
        off += (bytes + 255) & ~(size_t)255;
        return p;
    };
    u16*   Y16   = (u16*)  carve((size_t)4096 * 1024 * 2);
    u16*   NF16  = (u16*)  carve((size_t)4096 * 512 * 2);
    float* X032  = (float*)carve((size_t)4096 * 256 * 4);
    u16*   X016  = (u16*)  carve((size_t)4096 * 256 * 2);
    float* XH32  = (float*)carve((size_t)4096 * 256 * 4);
    float* XLN32 = (float*)carve((size_t)4096 * 256 * 4);
    u16*   XLN16 = (u16*)  carve((size_t)4096 * 256 * 2);
    float* XF32  = (float*)carve((size_t)4096 * 256 * 4);
    u16*   W1_16 = (u16*)  carve((size_t)1024 * 512 * 2);
    u16*   W2_16 = (u16*)  carve((size_t)256 * 1024 * 2);
    u16*   Wp16  = (u16*)  carve((size_t)256 * 256 * 2);
    u16*   W3_16 = (u16*)  carve((size_t)1024 * 256 * 2);
    u16*   W4_16 = (u16*)  carve((size_t)256 * 1024 * 2);
    float* B1    = (float*)carve(1024 * 4);
    float* B2    = (float*)carve(256 * 4);
    float* BP    = (float*)carve(256 * 4);
    float* B3    = (float*)carve(1024 * 4);
    float* B4    = (float*)carve(256 * 4);
    int*   NBR   = (int*)  carve((size_t)4096 * CAP * 4);
    int*   DEG   = (int*)  carve((size_t)4096 * 4);
    float* ASRC  = (float*)carve((size_t)4096 * 4 * 4);
    float* ATGT  = (float*)carve((size_t)4096 * 4 * 4);
    float* PART  = (float*)carve((size_t)128 * 1024 * 2 * 4);
    float* SCL1  = (float*)carve(512 * 4);
    float* SHF1  = (float*)carve(512 * 4);
    float* SCL2  = (float*)carve(1024 * 4);
    float* SHF2  = (float*)carve(1024 * 4);
    float* SCL3  = (float*)carve(256 * 4);
    float* SHF3  = (float*)carve(256 * 4);
    float* SCL4  = (float*)carve(1024 * 4);
    float* SHF4  = (float*)carve(1024 * 4);
    int*   FLAG  = (int*)  carve(256);
    (void)ws_size; (void)n_in; (void)in_sizes; (void)out_size;

    const int NB = 128, RPB = 4096 / 128;

    probe_adj_kernel<<<1, 64, 0, stream>>>(adj, FLAG);
    // neighbor lists early (independent of FFN chain)
    build_nbr_kernel<<<4096, 256, 0, stream>>>(adj, FLAG, NBR, DEG);

    // --- stage 1: BN1 fold + GEMM1 (Y = gelu(bn(nf)@W1^T+c1)) -> Y16
    colstats_partial<2, true><<<NB, 256, 0, stream>>>(nf, PART, NF16, RPB);
    colstats_final<<<2, 256, 0, stream>>>(PART, pre_g1, pre_b1, SCL1, SHF1, NB, 512);
    foldw_kernel<<<1024, 256, 0, stream>>>(pre_W1, SCL1, SHF1, pre_c1, W1_16, B1, 512);
    mfma_gemm<true, false, true><<<dim3(16, 64), 256, 0, stream>>>(
        NF16, W1_16, B1, nullptr, Y16, 4096, 1024, 512);

    // --- stage 2: BN2 fold + GEMM2 (X0) -> X032 + X016
    colstats_partial_b16<4><<<NB, 256, 0, stream>>>(Y16, PART, RPB);
    colstats_final<<<4, 256, 0, stream>>>(PART, pre_g2, pre_b2, SCL2, SHF2, NB, 1024);
    foldw_kernel<<<256, 256, 0, stream>>>(pre_W2, SCL2, SHF2, pre_c2, W2_16, B2, 1024);
    mfma_gemm<true, true, true><<<dim3(4, 64), 256, 0, stream>>>(
        Y16, W2_16, B2, X032, X016, 4096, 256, 1024);

    // --- stage 3: GEMM3 (XH = X0 @ Wp^T) -> XH32
    foldw_kernel<<<256, 256, 0, stream>>>(Wp, nullptr, nullptr, nullptr, Wp16, BP, 256);
    mfma_gemm<false, true, false><<<dim3(4, 64), 256, 0, stream>>>(
        X016, Wp16, nullptr, XH32, nullptr, 4096, 256, 256);

    // --- attention
    asrc_atgt_kernel<<<1024, 256, 0, stream>>>(XH32, Wa, ASRC, ATGT);
    attn_ln_kernel<<<4096, 256, 0, stream>>>(XH32, X032, ASRC, ATGT, NBR, DEG,
                                             ln_g, ln_b, XLN32, XLN16);

    // --- stage 4: BN3 fold + GEMM4 -> Y16
    colstats_partial<1, false><<<NB, 256, 0, stream>>>(XLN32, PART, nullptr, RPB);
    colstats_final<<<1, 256, 0, stream>>>(PART, post_g1, post_b1, SCL3, SHF3, NB, 256);
    foldw_kernel<<<1024, 256, 0, stream>>>(post_W1, SCL3, SHF3, post_c1, W3_16, B3, 256);
    mfma_gemm<true, false, true><<<dim3(16, 64), 256, 0, stream>>>(
        XLN16, W3_16, B3, nullptr, Y16, 4096, 1024, 256);

    // --- stage 5: BN4 fold + GEMM5 -> XF32
    colstats_partial_b16<4><<<NB, 256, 0, stream>>>(Y16, PART, RPB);
    colstats_final<<<4, 256, 0, stream>>>(PART, post_g2, post_b2, SCL4, SHF4, NB, 1024);
    foldw_kernel<<<256, 256, 0, stream>>>(post_W2, SCL4, SHF4, post_c2, W4_16, B4, 1024);
    mfma_gemm<true, true, false><<<dim3(4, 64), 256, 0, stream>>>(
        Y16, W4_16, B4, XF32, nullptr, 4096, 256, 1024);

    // --- logits
    logits_kernel<<<8192 / 8, 256, 0, stream>>>(XF32, idxs, Wl, cl, out);
}